// Round 1
// baseline (505.856 us; speedup 1.0000x reference)
//
#include <hip/hip_runtime.h>

#define DIM 64

// Kernel A: support = 0.9*x + 0.1*h0 ; out = 0.5 * (support @ W)
// One wave (64 lanes) per row. W staged in LDS (64*64*4 = 16 KiB).
__global__ __launch_bounds__(256) void support_gemm_kernel(
    const float* __restrict__ x, const float* __restrict__ h0,
    const float* __restrict__ weight, float* __restrict__ support,
    float* __restrict__ out, int n)
{
    __shared__ float wlds[DIM * DIM];
    for (int i = threadIdx.x; i < DIM * DIM; i += blockDim.x)
        wlds[i] = weight[i];
    __syncthreads();

    const int lane = threadIdx.x & 63;
    const int wavesPerBlock = blockDim.x >> 6;
    const int gwave = blockIdx.x * wavesPerBlock + (threadIdx.x >> 6);
    const int waveStride = gridDim.x * wavesPerBlock;

    for (int row = gwave; row < n; row += waveStride) {
        const long base = (long)row * DIM + lane;
        float s = 0.9f * x[base] + 0.1f * h0[base];
        support[base] = s;
        float acc = 0.0f;
        #pragma unroll
        for (int k = 0; k < DIM; ++k) {
            float sk = __shfl(s, k, 64);
            acc = fmaf(sk, wlds[k * DIM + lane], acc);
        }
        out[base] = 0.5f * acc;
    }
}

// Kernel B: out[row][j] += 0.5 * val * support[col][j], atomics.
// 64 consecutive threads share one edge (lane j = column).
__global__ __launch_bounds__(256) void spmm_atomic_kernel(
    const int* __restrict__ erow, const int* __restrict__ ecol,
    const float* __restrict__ eval_, const float* __restrict__ support,
    float* __restrict__ out, int e)
{
    const long total = (long)e * DIM;
    long idx = (long)blockIdx.x * blockDim.x + threadIdx.x;
    const long stride = (long)gridDim.x * blockDim.x;
    for (long t = idx; t < total; t += stride) {
        const int edge = (int)(t >> 6);
        const int j = (int)(t & 63);
        const int r = erow[edge];
        const int c = ecol[edge];
        const float v = eval_[edge];
        const float m = 0.5f * v * support[(long)c * DIM + j];
        atomicAdd(&out[(long)r * DIM + j], m);
    }
}

extern "C" void kernel_launch(void* const* d_in, const int* in_sizes, int n_in,
                              void* d_out, int out_size, void* d_ws, size_t ws_size,
                              hipStream_t stream) {
    const float* x      = (const float*)d_in[0];
    const float* h0     = (const float*)d_in[1];
    const int*   erow   = (const int*)d_in[2];
    const int*   ecol   = (const int*)d_in[3];
    const float* eval_  = (const float*)d_in[4];
    const float* weight = (const float*)d_in[5];
    float* out = (float*)d_out;
    float* support = (float*)d_ws;   // n*64 floats = 25.6 MB

    const int n = in_sizes[0] / DIM;
    const int e = in_sizes[2];

    // Kernel A: 2048 blocks x 4 waves = 8192 waves, grid-stride over rows.
    int gridA = 2048;
    support_gemm_kernel<<<gridA, 256, 0, stream>>>(x, h0, weight, support, out, n);

    // Kernel B: grid-stride over e*64 threads.
    int gridB = 16384;
    spmm_atomic_kernel<<<gridB, 256, 0, stream>>>(erow, ecol, eval_, support, out, e);
}

// Round 3
// 437.395 us; speedup vs baseline: 1.1565x; 1.1565x over previous
//
#include <hip/hip_runtime.h>
#include <hip/hip_bf16.h>

#define DIM 64

// ---------------- Kernel A: support + dense branch -------------------------
// Per block: 64 rows. Compute support = 0.9x+0.1h0 into LDS (+ store bf16
// and/or f32 copies to global), then 64x64 @ 64x64 GEMM (register-blocked
// 4x4 per thread, 16x16 threads) writing 0.5*(support@W) to out.
__global__ __launch_bounds__(256) void support_dense_kernel(
    const float* __restrict__ x, const float* __restrict__ h0,
    const float* __restrict__ weight,
    __hip_bfloat16* __restrict__ sup_bf,   // may be null
    float* __restrict__ sup_f32,           // may be null
    float* __restrict__ out, int n)
{
    __shared__ float s_tile[64][68];   // pad 4: banks (4r+k)%32, 2-way max (free)
    __shared__ float w_tile[64][68];

    const int tid = threadIdx.x;
    for (int i = tid; i < 64 * 64; i += 256)
        w_tile[i >> 6][i & 63] = weight[i];

    const int row0 = blockIdx.x * 64;

    // stage support: 4096 floats = 2048 float2, 8 per thread
    for (int p = tid; p < 2048; p += 256) {
        const int r = p >> 5;            // (2p)/64
        const int c = (p & 31) << 1;
        const int row = row0 + r;
        float2 s2;
        if (row < n) {
            const size_t base = (size_t)row * DIM + c;
            const float2 xv = *(const float2*)&x[base];
            const float2 hv = *(const float2*)&h0[base];
            s2.x = 0.9f * xv.x + 0.1f * hv.x;
            s2.y = 0.9f * xv.y + 0.1f * hv.y;
            if (sup_bf) {
                __hip_bfloat162 b2;
                b2.x = __float2bfloat16(s2.x);
                b2.y = __float2bfloat16(s2.y);
                *(__hip_bfloat162*)&sup_bf[base] = b2;
            }
            if (sup_f32) {
                *(float2*)&sup_f32[base] = s2;
            }
        } else {
            s2.x = 0.f; s2.y = 0.f;
        }
        s_tile[r][c] = s2.x;
        s_tile[r][c + 1] = s2.y;
    }
    __syncthreads();

    // GEMM: thread (tx,ty) computes rows r0..r0+3, cols c0..c0+3
    const int tx = tid & 15, ty = tid >> 4;
    const int r0 = ty * 4, c0 = tx * 4;
    float acc[4][4] = {};
    #pragma unroll
    for (int k = 0; k < 64; k += 4) {
        float4 a[4], b[4];
        #pragma unroll
        for (int i = 0; i < 4; ++i) a[i] = *(const float4*)&s_tile[r0 + i][k];
        #pragma unroll
        for (int j = 0; j < 4; ++j) b[j] = *(const float4*)&w_tile[k + j][c0];
        #pragma unroll
        for (int i = 0; i < 4; ++i) {
            acc[i][0] = fmaf(a[i].x, b[0].x, acc[i][0]);
            acc[i][1] = fmaf(a[i].x, b[0].y, acc[i][1]);
            acc[i][2] = fmaf(a[i].x, b[0].z, acc[i][2]);
            acc[i][3] = fmaf(a[i].x, b[0].w, acc[i][3]);
            acc[i][0] = fmaf(a[i].y, b[1].x, acc[i][0]);
            acc[i][1] = fmaf(a[i].y, b[1].y, acc[i][1]);
            acc[i][2] = fmaf(a[i].y, b[1].z, acc[i][2]);
            acc[i][3] = fmaf(a[i].y, b[1].w, acc[i][3]);
            acc[i][0] = fmaf(a[i].z, b[2].x, acc[i][0]);
            acc[i][1] = fmaf(a[i].z, b[2].y, acc[i][1]);
            acc[i][2] = fmaf(a[i].z, b[2].z, acc[i][2]);
            acc[i][3] = fmaf(a[i].z, b[2].w, acc[i][3]);
            acc[i][0] = fmaf(a[i].w, b[3].x, acc[i][0]);
            acc[i][1] = fmaf(a[i].w, b[3].y, acc[i][1]);
            acc[i][2] = fmaf(a[i].w, b[3].z, acc[i][2]);
            acc[i][3] = fmaf(a[i].w, b[3].w, acc[i][3]);
        }
    }
    #pragma unroll
    for (int i = 0; i < 4; ++i) {
        const int row = row0 + r0 + i;
        if (row < n) {
            float4 o;
            o.x = 0.5f * acc[i][0]; o.y = 0.5f * acc[i][1];
            o.z = 0.5f * acc[i][2]; o.w = 0.5f * acc[i][3];
            *(float4*)&out[(size_t)row * DIM + c0] = o;
        }
    }
}

// ---------------- CSR build ------------------------------------------------
__global__ __launch_bounds__(256) void hist_kernel(
    const int* __restrict__ erow, int* __restrict__ counts, int e)
{
    int idx = blockIdx.x * blockDim.x + threadIdx.x;
    const int stride = gridDim.x * blockDim.x;
    for (int i = idx; i < e; i += stride)
        atomicAdd(&counts[erow[i]], 1);
}

// scan1: per-block (1024 items) exclusive scan + block totals
__global__ __launch_bounds__(256) void scan1_kernel(
    const int* __restrict__ counts, int* __restrict__ ex,
    int* __restrict__ blockSums, int n)
{
    __shared__ int lds[256];
    const int t = threadIdx.x;
    const int base = blockIdx.x * 1024 + t * 4;
    int v[4]; int sum = 0;
    #pragma unroll
    for (int j = 0; j < 4; ++j) {
        const int idx = base + j;
        v[j] = (idx < n) ? counts[idx] : 0;
        sum += v[j];
    }
    lds[t] = sum;
    __syncthreads();
    #pragma unroll
    for (int off = 1; off < 256; off <<= 1) {
        const int y = (t >= off) ? lds[t - off] : 0;
        __syncthreads();
        lds[t] += y;
        __syncthreads();
    }
    const int excl_t = lds[t] - sum;
    if (t == 255) blockSums[blockIdx.x] = lds[255];
    int run = excl_t;
    #pragma unroll
    for (int j = 0; j < 4; ++j) {
        const int idx = base + j;
        if (idx < n) ex[idx] = run;
        run += v[j];
    }
}

// scan2: single block, exclusive scan of <=128 block sums
__global__ __launch_bounds__(128) void scan2_kernel(int* __restrict__ bs, int nb)
{
    __shared__ int lds[128];
    const int t = threadIdx.x;
    const int v = (t < nb) ? bs[t] : 0;
    lds[t] = v;
    __syncthreads();
    #pragma unroll
    for (int off = 1; off < 128; off <<= 1) {
        const int y = (t >= off) ? lds[t - off] : 0;
        __syncthreads();
        lds[t] += y;
        __syncthreads();
    }
    if (t < nb) bs[t] = lds[t] - v;
}

// scan3: add block offsets; produce rowStart + cursor; rowStart[n]=e
__global__ __launch_bounds__(256) void scan3_kernel(
    int* __restrict__ rowStart, int* __restrict__ cursor,
    const int* __restrict__ blockSums, int n, int e)
{
    const int i = blockIdx.x * blockDim.x + threadIdx.x;
    if (i < n) {
        const int v = rowStart[i] + blockSums[i >> 10];
        rowStart[i] = v;
        cursor[i] = v;
    }
    if (i == 0) rowStart[n] = e;
}

__global__ __launch_bounds__(256) void scatter_kernel(
    const int* __restrict__ erow, const int* __restrict__ ecol,
    const float* __restrict__ eval_, int* __restrict__ cursor,
    int2* __restrict__ cv, int e)
{
    int idx = blockIdx.x * blockDim.x + threadIdx.x;
    const int stride = gridDim.x * blockDim.x;
    for (int i = idx; i < e; i += stride) {
        const int r = erow[i];
        const int c = ecol[i];
        const float v = eval_[i];
        const int p = atomicAdd(&cursor[r], 1);
        cv[p] = make_int2(c, __float_as_int(v));
    }
}

// ---------------- Aggregate: one wave per row ------------------------------
__global__ __launch_bounds__(256) void aggregate_kernel(
    const int* __restrict__ rowStart, const int2* __restrict__ cv,
    const __hip_bfloat16* __restrict__ sup_bf, float* __restrict__ out, int n)
{
    const int row = blockIdx.x * 4 + (threadIdx.x >> 6);
    if (row >= n) return;
    const int lane = threadIdx.x & 63;
    const int s = rowStart[row], e = rowStart[row + 1];
    float acc = 0.f;
    int i = s;
    for (; i + 4 <= e; i += 4) {
        const int2 c0 = cv[i], c1 = cv[i + 1], c2 = cv[i + 2], c3 = cv[i + 3];
        const float m0 = __bfloat162float(sup_bf[(size_t)c0.x * DIM + lane]);
        const float m1 = __bfloat162float(sup_bf[(size_t)c1.x * DIM + lane]);
        const float m2 = __bfloat162float(sup_bf[(size_t)c2.x * DIM + lane]);
        const float m3 = __bfloat162float(sup_bf[(size_t)c3.x * DIM + lane]);
        acc = fmaf(__int_as_float(c0.y), m0, acc);
        acc = fmaf(__int_as_float(c1.y), m1, acc);
        acc = fmaf(__int_as_float(c2.y), m2, acc);
        acc = fmaf(__int_as_float(c3.y), m3, acc);
    }
    for (; i < e; ++i) {
        const int2 c0 = cv[i];
        acc = fmaf(__int_as_float(c0.y),
                   __bfloat162float(sup_bf[(size_t)c0.x * DIM + lane]), acc);
    }
    const size_t base = (size_t)row * DIM + lane;
    out[base] = fmaf(0.5f, acc, out[base]);
}

// ---------------- Fallback (old atomic path) -------------------------------
__global__ __launch_bounds__(256) void spmm_atomic_kernel(
    const int* __restrict__ erow, const int* __restrict__ ecol,
    const float* __restrict__ eval_, const float* __restrict__ support,
    float* __restrict__ out, int e)
{
    const long total = (long)e * DIM;
    long idx = (long)blockIdx.x * blockDim.x + threadIdx.x;
    const long stride = (long)gridDim.x * blockDim.x;
    for (long t = idx; t < total; t += stride) {
        const int edge = (int)(t >> 6);
        const int j = (int)(t & 63);
        const float m = 0.5f * eval_[edge] * support[(long)ecol[edge] * DIM + j];
        atomicAdd(&out[(long)erow[edge] * DIM + j], m);
    }
}

extern "C" void kernel_launch(void* const* d_in, const int* in_sizes, int n_in,
                              void* d_out, int out_size, void* d_ws, size_t ws_size,
                              hipStream_t stream) {
    const float* x      = (const float*)d_in[0];
    const float* h0     = (const float*)d_in[1];
    const int*   erow   = (const int*)d_in[2];
    const int*   ecol   = (const int*)d_in[3];
    const float* eval_  = (const float*)d_in[4];
    const float* weight = (const float*)d_in[5];
    float* out = (float*)d_out;

    const int n = in_sizes[0] / DIM;
    const int e = in_sizes[2];

    // ws layout
    char* wsb = (char*)d_ws;
    size_t off = 0;
    auto alloc = [&](size_t bytes) { size_t o = off; off = (off + bytes + 255) & ~255ULL; return o; };
    const size_t o_supbf = alloc((size_t)n * DIM * 2);
    const size_t o_cv    = alloc((size_t)e * 8);
    const size_t o_rowst = alloc((size_t)(n + 1) * 4);
    const size_t o_curs  = alloc((size_t)n * 4);
    const size_t o_cnts  = alloc((size_t)n * 4);
    const size_t o_bsums = alloc(512);
    const size_t need = off;

    const int nb1 = (n + 1023) / 1024;

    if (ws_size >= need && nb1 <= 128) {
        __hip_bfloat16* sup_bf = (__hip_bfloat16*)(wsb + o_supbf);
        int2* cv      = (int2*)(wsb + o_cv);
        int* rowStart = (int*)(wsb + o_rowst);
        int* cursor   = (int*)(wsb + o_curs);
        int* counts   = (int*)(wsb + o_cnts);
        int* bsums    = (int*)(wsb + o_bsums);

        hipMemsetAsync(counts, 0, (size_t)n * 4, stream);

        support_dense_kernel<<<(n + 63) / 64, 256, 0, stream>>>(
            x, h0, weight, sup_bf, nullptr, out, n);
        hist_kernel<<<2048, 256, 0, stream>>>(erow, counts, e);
        scan1_kernel<<<nb1, 256, 0, stream>>>(counts, rowStart, bsums, n);
        scan2_kernel<<<1, 128, 0, stream>>>(bsums, nb1);
        scan3_kernel<<<(n + 255) / 256, 256, 0, stream>>>(rowStart, cursor, bsums, n, e);
        scatter_kernel<<<2048, 256, 0, stream>>>(erow, ecol, eval_, cursor, cv, e);
        aggregate_kernel<<<(n + 3) / 4, 256, 0, stream>>>(rowStart, cv, sup_bf, out, n);
    } else {
        // fallback: old atomic path (requires n*DIM*4 bytes of ws)
        float* support = (float*)d_ws;
        support_dense_kernel<<<(n + 63) / 64, 256, 0, stream>>>(
            x, h0, weight, nullptr, support, out, n);
        spmm_atomic_kernel<<<16384, 256, 0, stream>>>(erow, ecol, eval_, support, out, e);
    }
}

// Round 4
// 374.249 us; speedup vs baseline: 1.3517x; 1.1687x over previous
//
#include <hip/hip_runtime.h>
#include <hip/hip_bf16.h>

#define DIM 64

// ---------------- Kernel A: support + dense branch -------------------------
__global__ __launch_bounds__(256) void support_dense_kernel(
    const float* __restrict__ x, const float* __restrict__ h0,
    const float* __restrict__ weight,
    __hip_bfloat16* __restrict__ sup_bf,   // may be null
    float* __restrict__ sup_f32,           // may be null
    float* __restrict__ out, int n)
{
    __shared__ float s_tile[64][68];
    __shared__ float w_tile[64][68];

    const int tid = threadIdx.x;
    for (int i = tid; i < 64 * 64; i += 256)
        w_tile[i >> 6][i & 63] = weight[i];

    const int row0 = blockIdx.x * 64;

    for (int p = tid; p < 2048; p += 256) {
        const int r = p >> 5;
        const int c = (p & 31) << 1;
        const int row = row0 + r;
        float2 s2;
        if (row < n) {
            const size_t base = (size_t)row * DIM + c;
            const float2 xv = *(const float2*)&x[base];
            const float2 hv = *(const float2*)&h0[base];
            s2.x = 0.9f * xv.x + 0.1f * hv.x;
            s2.y = 0.9f * xv.y + 0.1f * hv.y;
            if (sup_bf) {
                __hip_bfloat162 b2;
                b2.x = __float2bfloat16(s2.x);
                b2.y = __float2bfloat16(s2.y);
                *(__hip_bfloat162*)&sup_bf[base] = b2;
            }
            if (sup_f32) {
                *(float2*)&sup_f32[base] = s2;
            }
        } else {
            s2.x = 0.f; s2.y = 0.f;
        }
        s_tile[r][c] = s2.x;
        s_tile[r][c + 1] = s2.y;
    }
    __syncthreads();

    const int tx = tid & 15, ty = tid >> 4;
    const int r0 = ty * 4, c0 = tx * 4;
    float acc[4][4] = {};
    #pragma unroll
    for (int k = 0; k < 64; k += 4) {
        float4 a[4], b[4];
        #pragma unroll
        for (int i = 0; i < 4; ++i) a[i] = *(const float4*)&s_tile[r0 + i][k];
        #pragma unroll
        for (int j = 0; j < 4; ++j) b[j] = *(const float4*)&w_tile[k + j][c0];
        #pragma unroll
        for (int i = 0; i < 4; ++i) {
            acc[i][0] = fmaf(a[i].x, b[0].x, acc[i][0]);
            acc[i][1] = fmaf(a[i].x, b[0].y, acc[i][1]);
            acc[i][2] = fmaf(a[i].x, b[0].z, acc[i][2]);
            acc[i][3] = fmaf(a[i].x, b[0].w, acc[i][3]);
            acc[i][0] = fmaf(a[i].y, b[1].x, acc[i][0]);
            acc[i][1] = fmaf(a[i].y, b[1].y, acc[i][1]);
            acc[i][2] = fmaf(a[i].y, b[1].z, acc[i][2]);
            acc[i][3] = fmaf(a[i].y, b[1].w, acc[i][3]);
            acc[i][0] = fmaf(a[i].z, b[2].x, acc[i][0]);
            acc[i][1] = fmaf(a[i].z, b[2].y, acc[i][1]);
            acc[i][2] = fmaf(a[i].z, b[2].z, acc[i][2]);
            acc[i][3] = fmaf(a[i].z, b[2].w, acc[i][3]);
            acc[i][0] = fmaf(a[i].w, b[3].x, acc[i][0]);
            acc[i][1] = fmaf(a[i].w, b[3].y, acc[i][1]);
            acc[i][2] = fmaf(a[i].w, b[3].z, acc[i][2]);
            acc[i][3] = fmaf(a[i].w, b[3].w, acc[i][3]);
        }
    }
    #pragma unroll
    for (int i = 0; i < 4; ++i) {
        const int row = row0 + r0 + i;
        if (row < n) {
            float4 o;
            o.x = 0.5f * acc[i][0]; o.y = 0.5f * acc[i][1];
            o.z = 0.5f * acc[i][2]; o.w = 0.5f * acc[i][3];
            *(float4*)&out[(size_t)row * DIM + c0] = o;
        }
    }
}

// ---------------- CSR build ------------------------------------------------
__global__ __launch_bounds__(256) void hist_kernel(
    const int* __restrict__ erow, int* __restrict__ counts, int e)
{
    int idx = blockIdx.x * blockDim.x + threadIdx.x;
    const int stride = gridDim.x * blockDim.x;
    for (int i = idx; i < e; i += stride)
        atomicAdd(&counts[erow[i]], 1);
}

__global__ __launch_bounds__(256) void scan1_kernel(
    const int* __restrict__ counts, int* __restrict__ ex,
    int* __restrict__ blockSums, int n)
{
    __shared__ int lds[256];
    const int t = threadIdx.x;
    const int base = blockIdx.x * 1024 + t * 4;
    int v[4]; int sum = 0;
    #pragma unroll
    for (int j = 0; j < 4; ++j) {
        const int idx = base + j;
        v[j] = (idx < n) ? counts[idx] : 0;
        sum += v[j];
    }
    lds[t] = sum;
    __syncthreads();
    #pragma unroll
    for (int off = 1; off < 256; off <<= 1) {
        const int y = (t >= off) ? lds[t - off] : 0;
        __syncthreads();
        lds[t] += y;
        __syncthreads();
    }
    const int excl_t = lds[t] - sum;
    if (t == 255) blockSums[blockIdx.x] = lds[255];
    int run = excl_t;
    #pragma unroll
    for (int j = 0; j < 4; ++j) {
        const int idx = base + j;
        if (idx < n) ex[idx] = run;
        run += v[j];
    }
}

__global__ __launch_bounds__(128) void scan2_kernel(int* __restrict__ bs, int nb)
{
    __shared__ int lds[128];
    const int t = threadIdx.x;
    const int v = (t < nb) ? bs[t] : 0;
    lds[t] = v;
    __syncthreads();
    #pragma unroll
    for (int off = 1; off < 128; off <<= 1) {
        const int y = (t >= off) ? lds[t - off] : 0;
        __syncthreads();
        lds[t] += y;
        __syncthreads();
    }
    if (t < nb) bs[t] = lds[t] - v;
}

__global__ __launch_bounds__(256) void scan3_kernel(
    int* __restrict__ rowStart, int* __restrict__ cursor,
    const int* __restrict__ blockSums, int n, int e)
{
    const int i = blockIdx.x * blockDim.x + threadIdx.x;
    if (i < n) {
        const int v = rowStart[i] + blockSums[i >> 10];
        rowStart[i] = v;
        cursor[i] = v;
    }
    if (i == 0) rowStart[n] = e;
}

// XCD-partitioned scatter: blockIdx&7 ~ XCD id (round-robin dispatch).
// Each partition handles a disjoint 1/8 row range, so each cv cache line is
// dirtied in exactly one XCD's L2 -> written back to HBM once (12.8 MB, not
// 8x). Each partition re-scans the full edge list (L3-resident, cheap reads).
__global__ __launch_bounds__(256) void scatter_part_kernel(
    const int* __restrict__ erow, const int* __restrict__ ecol,
    const float* __restrict__ eval_, int* __restrict__ cursor,
    int2* __restrict__ cv, int e, int rlo_chunk)
{
    const int part = blockIdx.x & 7;
    const int bip  = blockIdx.x >> 3;
    const int nbp  = gridDim.x >> 3;
    const int rlo = part * rlo_chunk;
    const int rhi = rlo + rlo_chunk;   // last chunk may exceed n; harmless

    int idx = bip * blockDim.x + threadIdx.x;
    const int stride = nbp * blockDim.x;
    for (int i = idx; i < e; i += stride) {
        const int r = erow[i];
        if (r >= rlo && r < rhi) {
            const int c = ecol[i];
            const float v = eval_[i];
            const int p = atomicAdd(&cursor[r], 1);
            cv[p] = make_int2(c, __float_as_int(v));
        }
    }
}

// ---------------- Aggregate: one wave per row ------------------------------
__global__ __launch_bounds__(256) void aggregate_kernel(
    const int* __restrict__ rowStart, const int2* __restrict__ cv,
    const __hip_bfloat16* __restrict__ sup_bf, float* __restrict__ out, int n)
{
    const int row = blockIdx.x * 4 + (threadIdx.x >> 6);
    if (row >= n) return;
    const int lane = threadIdx.x & 63;
    const int s = rowStart[row], e = rowStart[row + 1];
    float acc = 0.f;
    int i = s;
    for (; i + 4 <= e; i += 4) {
        const int2 c0 = cv[i], c1 = cv[i + 1], c2 = cv[i + 2], c3 = cv[i + 3];
        const float m0 = __bfloat162float(sup_bf[(size_t)c0.x * DIM + lane]);
        const float m1 = __bfloat162float(sup_bf[(size_t)c1.x * DIM + lane]);
        const float m2 = __bfloat162float(sup_bf[(size_t)c2.x * DIM + lane]);
        const float m3 = __bfloat162float(sup_bf[(size_t)c3.x * DIM + lane]);
        acc = fmaf(__int_as_float(c0.y), m0, acc);
        acc = fmaf(__int_as_float(c1.y), m1, acc);
        acc = fmaf(__int_as_float(c2.y), m2, acc);
        acc = fmaf(__int_as_float(c3.y), m3, acc);
    }
    for (; i < e; ++i) {
        const int2 c0 = cv[i];
        acc = fmaf(__int_as_float(c0.y),
                   __bfloat162float(sup_bf[(size_t)c0.x * DIM + lane]), acc);
    }
    const size_t base = (size_t)row * DIM + lane;
    out[base] = fmaf(0.5f, acc, out[base]);
}

// ---------------- Fallback (old atomic path) -------------------------------
__global__ __launch_bounds__(256) void spmm_atomic_kernel(
    const int* __restrict__ erow, const int* __restrict__ ecol,
    const float* __restrict__ eval_, const float* __restrict__ support,
    float* __restrict__ out, int e)
{
    const long total = (long)e * DIM;
    long idx = (long)blockIdx.x * blockDim.x + threadIdx.x;
    const long stride = (long)gridDim.x * blockDim.x;
    for (long t = idx; t < total; t += stride) {
        const int edge = (int)(t >> 6);
        const int j = (int)(t & 63);
        const float m = 0.5f * eval_[edge] * support[(long)ecol[edge] * DIM + j];
        atomicAdd(&out[(long)erow[edge] * DIM + j], m);
    }
}

extern "C" void kernel_launch(void* const* d_in, const int* in_sizes, int n_in,
                              void* d_out, int out_size, void* d_ws, size_t ws_size,
                              hipStream_t stream) {
    const float* x      = (const float*)d_in[0];
    const float* h0     = (const float*)d_in[1];
    const int*   erow   = (const int*)d_in[2];
    const int*   ecol   = (const int*)d_in[3];
    const float* eval_  = (const float*)d_in[4];
    const float* weight = (const float*)d_in[5];
    float* out = (float*)d_out;

    const int n = in_sizes[0] / DIM;
    const int e = in_sizes[2];

    char* wsb = (char*)d_ws;
    size_t off = 0;
    auto alloc = [&](size_t bytes) { size_t o = off; off = (off + bytes + 255) & ~255ULL; return o; };
    const size_t o_supbf = alloc((size_t)n * DIM * 2);
    const size_t o_cv    = alloc((size_t)e * 8);
    const size_t o_rowst = alloc((size_t)(n + 1) * 4);
    const size_t o_curs  = alloc((size_t)n * 4);
    const size_t o_cnts  = alloc((size_t)n * 4);
    const size_t o_bsums = alloc(512);
    const size_t need = off;

    const int nb1 = (n + 1023) / 1024;

    if (ws_size >= need && nb1 <= 128) {
        __hip_bfloat16* sup_bf = (__hip_bfloat16*)(wsb + o_supbf);
        int2* cv      = (int2*)(wsb + o_cv);
        int* rowStart = (int*)(wsb + o_rowst);
        int* cursor   = (int*)(wsb + o_curs);
        int* counts   = (int*)(wsb + o_cnts);
        int* bsums    = (int*)(wsb + o_bsums);

        hipMemsetAsync(counts, 0, (size_t)n * 4, stream);

        support_dense_kernel<<<(n + 63) / 64, 256, 0, stream>>>(
            x, h0, weight, sup_bf, nullptr, out, n);
        hist_kernel<<<2048, 256, 0, stream>>>(erow, counts, e);
        scan1_kernel<<<nb1, 256, 0, stream>>>(counts, rowStart, bsums, n);
        scan2_kernel<<<1, 128, 0, stream>>>(bsums, nb1);
        scan3_kernel<<<(n + 255) / 256, 256, 0, stream>>>(rowStart, cursor, bsums, n, e);

        const int rchunk = (n + 7) / 8;
        scatter_part_kernel<<<4096, 256, 0, stream>>>(erow, ecol, eval_, cursor, cv, e, rchunk);

        aggregate_kernel<<<(n + 3) / 4, 256, 0, stream>>>(rowStart, cv, sup_bf, out, n);
    } else {
        float* support = (float*)d_ws;
        support_dense_kernel<<<(n + 63) / 64, 256, 0, stream>>>(
            x, h0, weight, nullptr, support, out, n);
        spmm_atomic_kernel<<<16384, 256, 0, stream>>>(erow, ecol, eval_, support, out, e);
    }
}

// Round 5
// 358.857 us; speedup vs baseline: 1.4096x; 1.0429x over previous
//
#include <hip/hip_runtime.h>
#include <hip/hip_bf16.h>

#define DIM 64

__device__ __forceinline__ int   nt_i(const int* p)   { return __builtin_nontemporal_load(p); }
__device__ __forceinline__ float nt_f(const float* p) { return __builtin_nontemporal_load(p); }
__device__ __forceinline__ long long nt_ll(const void* p) {
    return __builtin_nontemporal_load((const long long*)p);
}

// ---------------- support = 0.9x + 0.1h0 -> bf16 (streaming) --------------
__global__ __launch_bounds__(256) void support_bf16_kernel(
    const float* __restrict__ x, const float* __restrict__ h0,
    __hip_bfloat16* __restrict__ sup_bf, long total4)
{
    long idx = (long)blockIdx.x * blockDim.x + threadIdx.x;
    const long stride = (long)gridDim.x * blockDim.x;
    for (long t = idx; t < total4; t += stride) {
        const float4 xv = ((const float4*)x)[t];
        const float4 hv = ((const float4*)h0)[t];
        union { ushort4 u4; __hip_bfloat16 h[4]; } cvt;
        cvt.h[0] = __float2bfloat16(0.9f * xv.x + 0.1f * hv.x);
        cvt.h[1] = __float2bfloat16(0.9f * xv.y + 0.1f * hv.y);
        cvt.h[2] = __float2bfloat16(0.9f * xv.z + 0.1f * hv.z);
        cvt.h[3] = __float2bfloat16(0.9f * xv.w + 0.1f * hv.w);
        ((ushort4*)sup_bf)[t] = cvt.u4;
    }
}

// ---------------- dense branch: out = 0.5 * (sup @ W) ---------------------
__global__ __launch_bounds__(256) void dense_gemm_kernel(
    const __hip_bfloat16* __restrict__ sup_bf,
    const float* __restrict__ weight, float* __restrict__ out, int n)
{
    __shared__ float s_tile[64][68];
    __shared__ float w_tile[64][68];

    const int tid = threadIdx.x;
    for (int i = tid; i < 64 * 64; i += 256)
        w_tile[i >> 6][i & 63] = weight[i];

    const int row0 = blockIdx.x * 64;
    for (int p = tid; p < 1024; p += 256) {
        const int r = p >> 4;
        const int c = (p & 15) << 2;
        const int row = row0 + r;
        if (row < n) {
            union { ushort4 u4; __hip_bfloat16 h[4]; } cvt;
            cvt.u4 = *(const ushort4*)&sup_bf[(size_t)row * DIM + c];
            s_tile[r][c]     = __bfloat162float(cvt.h[0]);
            s_tile[r][c + 1] = __bfloat162float(cvt.h[1]);
            s_tile[r][c + 2] = __bfloat162float(cvt.h[2]);
            s_tile[r][c + 3] = __bfloat162float(cvt.h[3]);
        } else {
            s_tile[r][c] = 0.f; s_tile[r][c+1] = 0.f;
            s_tile[r][c+2] = 0.f; s_tile[r][c+3] = 0.f;
        }
    }
    __syncthreads();

    const int tx = tid & 15, ty = tid >> 4;
    const int r0 = ty * 4, c0 = tx * 4;
    float acc[4][4] = {};
    #pragma unroll 2
    for (int k = 0; k < 64; k += 4) {
        float4 a[4], b[4];
        #pragma unroll
        for (int i = 0; i < 4; ++i) a[i] = *(const float4*)&s_tile[r0 + i][k];
        #pragma unroll
        for (int j = 0; j < 4; ++j) b[j] = *(const float4*)&w_tile[k + j][c0];
        #pragma unroll
        for (int i = 0; i < 4; ++i) {
            acc[i][0] = fmaf(a[i].x, b[0].x, acc[i][0]);
            acc[i][1] = fmaf(a[i].x, b[0].y, acc[i][1]);
            acc[i][2] = fmaf(a[i].x, b[0].z, acc[i][2]);
            acc[i][3] = fmaf(a[i].x, b[0].w, acc[i][3]);
            acc[i][0] = fmaf(a[i].y, b[1].x, acc[i][0]);
            acc[i][1] = fmaf(a[i].y, b[1].y, acc[i][1]);
            acc[i][2] = fmaf(a[i].y, b[1].z, acc[i][2]);
            acc[i][3] = fmaf(a[i].y, b[1].w, acc[i][3]);
            acc[i][0] = fmaf(a[i].z, b[2].x, acc[i][0]);
            acc[i][1] = fmaf(a[i].z, b[2].y, acc[i][1]);
            acc[i][2] = fmaf(a[i].z, b[2].z, acc[i][2]);
            acc[i][3] = fmaf(a[i].z, b[2].w, acc[i][3]);
            acc[i][0] = fmaf(a[i].w, b[3].x, acc[i][0]);
            acc[i][1] = fmaf(a[i].w, b[3].y, acc[i][1]);
            acc[i][2] = fmaf(a[i].w, b[3].z, acc[i][2]);
            acc[i][3] = fmaf(a[i].w, b[3].w, acc[i][3]);
        }
    }
    #pragma unroll
    for (int i = 0; i < 4; ++i) {
        const int row = row0 + r0 + i;
        if (row < n) {
            float4 o;
            o.x = 0.5f * acc[i][0]; o.y = 0.5f * acc[i][1];
            o.z = 0.5f * acc[i][2]; o.w = 0.5f * acc[i][3];
            *(float4*)&out[(size_t)row * DIM + c0] = o;
        }
    }
}

// ---------------- CSR build ------------------------------------------------
__global__ __launch_bounds__(256) void hist_kernel(
    const int* __restrict__ erow, int* __restrict__ counts, int e)
{
    int idx = blockIdx.x * blockDim.x + threadIdx.x;
    const int stride = gridDim.x * blockDim.x;
    for (int i = idx; i < e; i += stride)
        atomicAdd(&counts[nt_i(&erow[i])], 1);
}

__global__ __launch_bounds__(256) void scan1_kernel(
    const int* __restrict__ counts, int* __restrict__ ex,
    int* __restrict__ blockSums, int n)
{
    __shared__ int lds[256];
    const int t = threadIdx.x;
    const int base = blockIdx.x * 1024 + t * 4;
    int v[4]; int sum = 0;
    #pragma unroll
    for (int j = 0; j < 4; ++j) {
        const int idx = base + j;
        v[j] = (idx < n) ? counts[idx] : 0;
        sum += v[j];
    }
    lds[t] = sum;
    __syncthreads();
    #pragma unroll
    for (int off = 1; off < 256; off <<= 1) {
        const int y = (t >= off) ? lds[t - off] : 0;
        __syncthreads();
        lds[t] += y;
        __syncthreads();
    }
    const int excl_t = lds[t] - sum;
    if (t == 255) blockSums[blockIdx.x] = lds[255];
    int run = excl_t;
    #pragma unroll
    for (int j = 0; j < 4; ++j) {
        const int idx = base + j;
        if (idx < n) ex[idx] = run;
        run += v[j];
    }
}

__global__ __launch_bounds__(128) void scan2_kernel(int* __restrict__ bs, int nb)
{
    __shared__ int lds[128];
    const int t = threadIdx.x;
    const int v = (t < nb) ? bs[t] : 0;
    lds[t] = v;
    __syncthreads();
    #pragma unroll
    for (int off = 1; off < 128; off <<= 1) {
        const int y = (t >= off) ? lds[t - off] : 0;
        __syncthreads();
        lds[t] += y;
        __syncthreads();
    }
    if (t < nb) bs[t] = lds[t] - v;
}

__global__ __launch_bounds__(256) void scan3_kernel(
    int* __restrict__ rowStart, int* __restrict__ cursor,
    const int* __restrict__ blockSums, int n, int e)
{
    const int i = blockIdx.x * blockDim.x + threadIdx.x;
    if (i < n) {
        const int v = rowStart[i] + blockSums[i >> 10];
        rowStart[i] = v;
        cursor[i] = v;
    }
    if (i == 0) rowStart[n] = e;
}

// XCD-partitioned scatter with non-temporal streaming reads.
__global__ __launch_bounds__(256) void scatter_part_kernel(
    const int* __restrict__ erow, const int* __restrict__ ecol,
    const float* __restrict__ eval_, int* __restrict__ cursor,
    int2* __restrict__ cv, int e, int rlo_chunk)
{
    const int part = blockIdx.x & 7;
    const int bip  = blockIdx.x >> 3;
    const int nbp  = gridDim.x >> 3;
    const int rlo = part * rlo_chunk;
    const int rhi = rlo + rlo_chunk;

    int idx = bip * blockDim.x + threadIdx.x;
    const int stride = nbp * blockDim.x;
    for (int i = idx; i < e; i += stride) {
        const int r = nt_i(&erow[i]);
        if (r >= rlo && r < rhi) {
            const int c = nt_i(&ecol[i]);
            const float v = nt_f(&eval_[i]);
            const int p = atomicAdd(&cursor[r], 1);
            cv[p] = make_int2(c, __float_as_int(v));
        }
    }
}

// ---------------- Aggregate: one wave per row ------------------------------
__global__ __launch_bounds__(256) void aggregate_kernel(
    const int* __restrict__ rowStart, const int2* __restrict__ cv,
    const __hip_bfloat16* __restrict__ sup_bf, float* __restrict__ out, int n)
{
    const int row = blockIdx.x * 4 + (threadIdx.x >> 6);
    if (row >= n) return;
    const int lane = threadIdx.x & 63;
    const int s = rowStart[row], e = rowStart[row + 1];
    float acc = 0.f;
    int i = s;
    for (; i + 4 <= e; i += 4) {
        const long long q0 = nt_ll(&cv[i]);
        const long long q1 = nt_ll(&cv[i + 1]);
        const long long q2 = nt_ll(&cv[i + 2]);
        const long long q3 = nt_ll(&cv[i + 3]);
        const float m0 = __bfloat162float(sup_bf[(size_t)(int)q0 * DIM + lane]);
        const float m1 = __bfloat162float(sup_bf[(size_t)(int)q1 * DIM + lane]);
        const float m2 = __bfloat162float(sup_bf[(size_t)(int)q2 * DIM + lane]);
        const float m3 = __bfloat162float(sup_bf[(size_t)(int)q3 * DIM + lane]);
        acc = fmaf(__int_as_float((int)(q0 >> 32)), m0, acc);
        acc = fmaf(__int_as_float((int)(q1 >> 32)), m1, acc);
        acc = fmaf(__int_as_float((int)(q2 >> 32)), m2, acc);
        acc = fmaf(__int_as_float((int)(q3 >> 32)), m3, acc);
    }
    for (; i < e; ++i) {
        const long long q0 = nt_ll(&cv[i]);
        acc = fmaf(__int_as_float((int)(q0 >> 32)),
                   __bfloat162float(sup_bf[(size_t)(int)q0 * DIM + lane]), acc);
    }
    const size_t base = (size_t)row * DIM + lane;
    out[base] = fmaf(0.5f, acc, out[base]);
}

// ---------------- Fallback (atomic path, f32 support) ----------------------
__global__ __launch_bounds__(256) void support_f32_kernel(
    const float* __restrict__ x, const float* __restrict__ h0,
    float* __restrict__ sup, long total4)
{
    long idx = (long)blockIdx.x * blockDim.x + threadIdx.x;
    const long stride = (long)gridDim.x * blockDim.x;
    for (long t = idx; t < total4; t += stride) {
        const float4 xv = ((const float4*)x)[t];
        const float4 hv = ((const float4*)h0)[t];
        float4 s;
        s.x = 0.9f * xv.x + 0.1f * hv.x;
        s.y = 0.9f * xv.y + 0.1f * hv.y;
        s.z = 0.9f * xv.z + 0.1f * hv.z;
        s.w = 0.9f * xv.w + 0.1f * hv.w;
        ((float4*)sup)[t] = s;
    }
}

__global__ __launch_bounds__(256) void dense_gemm_f32_kernel(
    const float* __restrict__ sup, const float* __restrict__ weight,
    float* __restrict__ out, int n)
{
    __shared__ float s_tile[64][68];
    __shared__ float w_tile[64][68];
    const int tid = threadIdx.x;
    for (int i = tid; i < 64 * 64; i += 256)
        w_tile[i >> 6][i & 63] = weight[i];
    const int row0 = blockIdx.x * 64;
    for (int p = tid; p < 2048; p += 256) {
        const int r = p >> 5;
        const int c = (p & 31) << 1;
        const int row = row0 + r;
        float2 s2 = make_float2(0.f, 0.f);
        if (row < n) s2 = *(const float2*)&sup[(size_t)row * DIM + c];
        s_tile[r][c] = s2.x; s_tile[r][c + 1] = s2.y;
    }
    __syncthreads();
    const int tx = tid & 15, ty = tid >> 4;
    const int r0 = ty * 4, c0 = tx * 4;
    float acc[4][4] = {};
    #pragma unroll 2
    for (int k = 0; k < 64; k += 4) {
        float4 a[4], b[4];
        #pragma unroll
        for (int i = 0; i < 4; ++i) a[i] = *(const float4*)&s_tile[r0 + i][k];
        #pragma unroll
        for (int j = 0; j < 4; ++j) b[j] = *(const float4*)&w_tile[k + j][c0];
        #pragma unroll
        for (int i = 0; i < 4; ++i) {
            acc[i][0] = fmaf(a[i].x, b[0].x, acc[i][0]);
            acc[i][1] = fmaf(a[i].x, b[0].y, acc[i][1]);
            acc[i][2] = fmaf(a[i].x, b[0].z, acc[i][2]);
            acc[i][3] = fmaf(a[i].x, b[0].w, acc[i][3]);
            acc[i][0] = fmaf(a[i].y, b[1].x, acc[i][0]);
            acc[i][1] = fmaf(a[i].y, b[1].y, acc[i][1]);
            acc[i][2] = fmaf(a[i].y, b[1].z, acc[i][2]);
            acc[i][3] = fmaf(a[i].y, b[1].w, acc[i][3]);
            acc[i][0] = fmaf(a[i].z, b[2].x, acc[i][0]);
            acc[i][1] = fmaf(a[i].z, b[2].y, acc[i][1]);
            acc[i][2] = fmaf(a[i].z, b[2].z, acc[i][2]);
            acc[i][3] = fmaf(a[i].z, b[2].w, acc[i][3]);
            acc[i][0] = fmaf(a[i].w, b[3].x, acc[i][0]);
            acc[i][1] = fmaf(a[i].w, b[3].y, acc[i][1]);
            acc[i][2] = fmaf(a[i].w, b[3].z, acc[i][2]);
            acc[i][3] = fmaf(a[i].w, b[3].w, acc[i][3]);
        }
    }
    #pragma unroll
    for (int i = 0; i < 4; ++i) {
        const int row = row0 + r0 + i;
        if (row < n) {
            float4 o;
            o.x = 0.5f * acc[i][0]; o.y = 0.5f * acc[i][1];
            o.z = 0.5f * acc[i][2]; o.w = 0.5f * acc[i][3];
            *(float4*)&out[(size_t)row * DIM + c0] = o;
        }
    }
}

__global__ __launch_bounds__(256) void spmm_atomic_kernel(
    const int* __restrict__ erow, const int* __restrict__ ecol,
    const float* __restrict__ eval_, const float* __restrict__ support,
    float* __restrict__ out, int e)
{
    const long total = (long)e * DIM;
    long idx = (long)blockIdx.x * blockDim.x + threadIdx.x;
    const long stride = (long)gridDim.x * blockDim.x;
    for (long t = idx; t < total; t += stride) {
        const int edge = (int)(t >> 6);
        const int j = (int)(t & 63);
        const float m = 0.5f * eval_[edge] * support[(long)ecol[edge] * DIM + j];
        atomicAdd(&out[(long)erow[edge] * DIM + j], m);
    }
}

extern "C" void kernel_launch(void* const* d_in, const int* in_sizes, int n_in,
                              void* d_out, int out_size, void* d_ws, size_t ws_size,
                              hipStream_t stream) {
    const float* x      = (const float*)d_in[0];
    const float* h0     = (const float*)d_in[1];
    const int*   erow   = (const int*)d_in[2];
    const int*   ecol   = (const int*)d_in[3];
    const float* eval_  = (const float*)d_in[4];
    const float* weight = (const float*)d_in[5];
    float* out = (float*)d_out;

    const int n = in_sizes[0] / DIM;
    const int e = in_sizes[2];

    char* wsb = (char*)d_ws;
    size_t off = 0;
    auto alloc = [&](size_t bytes) { size_t o = off; off = (off + bytes + 255) & ~255ULL; return o; };
    const size_t o_supbf = alloc((size_t)n * DIM * 2);
    const size_t o_cv    = alloc((size_t)e * 8);
    const size_t o_rowst = alloc((size_t)(n + 1) * 4);
    const size_t o_curs  = alloc((size_t)n * 4);
    const size_t o_cnts  = alloc((size_t)n * 4);
    const size_t o_bsums = alloc(512);
    const size_t need = off;

    const int nb1 = (n + 1023) / 1024;
    const long total4 = (long)n * DIM / 4;

    if (ws_size >= need && nb1 <= 128) {
        __hip_bfloat16* sup_bf = (__hip_bfloat16*)(wsb + o_supbf);
        int2* cv      = (int2*)(wsb + o_cv);
        int* rowStart = (int*)(wsb + o_rowst);
        int* cursor   = (int*)(wsb + o_curs);
        int* counts   = (int*)(wsb + o_cnts);
        int* bsums    = (int*)(wsb + o_bsums);

        hipMemsetAsync(counts, 0, (size_t)n * 4, stream);

        support_bf16_kernel<<<2048, 256, 0, stream>>>(x, h0, sup_bf, total4);
        hist_kernel<<<2048, 256, 0, stream>>>(erow, counts, e);
        scan1_kernel<<<nb1, 256, 0, stream>>>(counts, rowStart, bsums, n);
        scan2_kernel<<<1, 128, 0, stream>>>(bsums, nb1);
        scan3_kernel<<<(n + 255) / 256, 256, 0, stream>>>(rowStart, cursor, bsums, n, e);

        dense_gemm_kernel<<<(n + 63) / 64, 256, 0, stream>>>(sup_bf, weight, out, n);

        const int rchunk = (n + 7) / 8;
        scatter_part_kernel<<<4096, 256, 0, stream>>>(erow, ecol, eval_, cursor, cv, e, rchunk);

        aggregate_kernel<<<(n + 3) / 4, 256, 0, stream>>>(rowStart, cv, sup_bf, out, n);
    } else {
        float* support = (float*)d_ws;
        support_f32_kernel<<<2048, 256, 0, stream>>>(x, h0, support, total4);
        dense_gemm_f32_kernel<<<(n + 63) / 64, 256, 0, stream>>>(support, weight, out, n);
        spmm_atomic_kernel<<<16384, 256, 0, stream>>>(erow, ecol, eval_, support, out, e);
    }
}

// Round 7
// 323.372 us; speedup vs baseline: 1.5643x; 1.1097x over previous
//
#include <hip/hip_runtime.h>
#include <hip/hip_bf16.h>

#define DIM 64

__device__ __forceinline__ int   nt_i(const int* p)   { return __builtin_nontemporal_load(p); }
__device__ __forceinline__ float nt_f(const float* p) { return __builtin_nontemporal_load(p); }
__device__ __forceinline__ float bfbits(unsigned short u) {
    return __uint_as_float(((unsigned)u) << 16);
}

// ---------------- support = 0.9x + 0.1h0 -> bf16 (streaming) --------------
__global__ __launch_bounds__(256) void support_bf16_kernel(
    const float* __restrict__ x, const float* __restrict__ h0,
    __hip_bfloat16* __restrict__ sup_bf, long total4)
{
    long idx = (long)blockIdx.x * blockDim.x + threadIdx.x;
    const long stride = (long)gridDim.x * blockDim.x;
    for (long t = idx; t < total4; t += stride) {
        const float4 xv = ((const float4*)x)[t];
        const float4 hv = ((const float4*)h0)[t];
        union { ushort4 u4; __hip_bfloat16 h[4]; } cvt;
        cvt.h[0] = __float2bfloat16(0.9f * xv.x + 0.1f * hv.x);
        cvt.h[1] = __float2bfloat16(0.9f * xv.y + 0.1f * hv.y);
        cvt.h[2] = __float2bfloat16(0.9f * xv.z + 0.1f * hv.z);
        cvt.h[3] = __float2bfloat16(0.9f * xv.w + 0.1f * hv.w);
        ((ushort4*)sup_bf)[t] = cvt.u4;
    }
}

// ---------------- dense branch: out = 0.5 * (sup @ W) ---------------------
__global__ __launch_bounds__(256) void dense_gemm_kernel(
    const __hip_bfloat16* __restrict__ sup_bf,
    const float* __restrict__ weight, float* __restrict__ out, int n)
{
    __shared__ float s_tile[64][68];
    __shared__ float w_tile[64][68];

    const int tid = threadIdx.x;
    for (int i = tid; i < 64 * 64; i += 256)
        w_tile[i >> 6][i & 63] = weight[i];

    const int row0 = blockIdx.x * 64;
    for (int p = tid; p < 1024; p += 256) {
        const int r = p >> 4;
        const int c = (p & 15) << 2;
        const int row = row0 + r;
        if (row < n) {
            const ushort4 u = *(const ushort4*)&sup_bf[(size_t)row * DIM + c];
            s_tile[r][c]     = bfbits(u.x);
            s_tile[r][c + 1] = bfbits(u.y);
            s_tile[r][c + 2] = bfbits(u.z);
            s_tile[r][c + 3] = bfbits(u.w);
        } else {
            s_tile[r][c] = 0.f; s_tile[r][c+1] = 0.f;
            s_tile[r][c+2] = 0.f; s_tile[r][c+3] = 0.f;
        }
    }
    __syncthreads();

    const int tx = tid & 15, ty = tid >> 4;
    const int r0 = ty * 4, c0 = tx * 4;
    float acc[4][4] = {};
    #pragma unroll 2
    for (int k = 0; k < 64; k += 4) {
        float4 a[4], b[4];
        #pragma unroll
        for (int i = 0; i < 4; ++i) a[i] = *(const float4*)&s_tile[r0 + i][k];
        #pragma unroll
        for (int j = 0; j < 4; ++j) b[j] = *(const float4*)&w_tile[k + j][c0];
        #pragma unroll
        for (int i = 0; i < 4; ++i) {
            acc[i][0] = fmaf(a[i].x, b[0].x, acc[i][0]);
            acc[i][1] = fmaf(a[i].x, b[0].y, acc[i][1]);
            acc[i][2] = fmaf(a[i].x, b[0].z, acc[i][2]);
            acc[i][3] = fmaf(a[i].x, b[0].w, acc[i][3]);
            acc[i][0] = fmaf(a[i].y, b[1].x, acc[i][0]);
            acc[i][1] = fmaf(a[i].y, b[1].y, acc[i][1]);
            acc[i][2] = fmaf(a[i].y, b[1].z, acc[i][2]);
            acc[i][3] = fmaf(a[i].y, b[1].w, acc[i][3]);
            acc[i][0] = fmaf(a[i].z, b[2].x, acc[i][0]);
            acc[i][1] = fmaf(a[i].z, b[2].y, acc[i][1]);
            acc[i][2] = fmaf(a[i].z, b[2].z, acc[i][2]);
            acc[i][3] = fmaf(a[i].z, b[2].w, acc[i][3]);
            acc[i][0] = fmaf(a[i].w, b[3].x, acc[i][0]);
            acc[i][1] = fmaf(a[i].w, b[3].y, acc[i][1]);
            acc[i][2] = fmaf(a[i].w, b[3].z, acc[i][2]);
            acc[i][3] = fmaf(a[i].w, b[3].w, acc[i][3]);
        }
    }
    #pragma unroll
    for (int i = 0; i < 4; ++i) {
        const int row = row0 + r0 + i;
        if (row < n) {
            float4 o;
            o.x = 0.5f * acc[i][0]; o.y = 0.5f * acc[i][1];
            o.z = 0.5f * acc[i][2]; o.w = 0.5f * acc[i][3];
            *(float4*)&out[(size_t)row * DIM + c0] = o;
        }
    }
}

// ---------------- CSR build ------------------------------------------------
__global__ __launch_bounds__(256) void hist_kernel(
    const int* __restrict__ erow, int* __restrict__ counts, int e)
{
    const int e4 = e >> 2;
    int idx = blockIdx.x * blockDim.x + threadIdx.x;
    const int stride = gridDim.x * blockDim.x;
    for (int i = idx; i < e4; i += stride) {
        const int r0 = nt_i(&erow[i * 4]);
        const int r1 = nt_i(&erow[i * 4 + 1]);
        const int r2 = nt_i(&erow[i * 4 + 2]);
        const int r3 = nt_i(&erow[i * 4 + 3]);
        atomicAdd(&counts[r0], 1);
        atomicAdd(&counts[r1], 1);
        atomicAdd(&counts[r2], 1);
        atomicAdd(&counts[r3], 1);
    }
    for (int i = (e4 << 2) + idx; i < e; i += stride)
        atomicAdd(&counts[nt_i(&erow[i])], 1);
}

__global__ __launch_bounds__(256) void scan1_kernel(
    const int* __restrict__ counts, int* __restrict__ ex,
    int* __restrict__ blockSums, int n)
{
    __shared__ int lds[256];
    const int t = threadIdx.x;
    const int base = blockIdx.x * 1024 + t * 4;
    int v[4]; int sum = 0;
    #pragma unroll
    for (int j = 0; j < 4; ++j) {
        const int idx = base + j;
        v[j] = (idx < n) ? counts[idx] : 0;
        sum += v[j];
    }
    lds[t] = sum;
    __syncthreads();
    #pragma unroll
    for (int off = 1; off < 256; off <<= 1) {
        const int y = (t >= off) ? lds[t - off] : 0;
        __syncthreads();
        lds[t] += y;
        __syncthreads();
    }
    const int excl_t = lds[t] - sum;
    if (t == 255) blockSums[blockIdx.x] = lds[255];
    int run = excl_t;
    #pragma unroll
    for (int j = 0; j < 4; ++j) {
        const int idx = base + j;
        if (idx < n) ex[idx] = run;
        run += v[j];
    }
}

__global__ __launch_bounds__(128) void scan2_kernel(int* __restrict__ bs, int nb)
{
    __shared__ int lds[128];
    const int t = threadIdx.x;
    const int v = (t < nb) ? bs[t] : 0;
    lds[t] = v;
    __syncthreads();
    #pragma unroll
    for (int off = 1; off < 128; off <<= 1) {
        const int y = (t >= off) ? lds[t - off] : 0;
        __syncthreads();
        lds[t] += y;
        __syncthreads();
    }
    if (t < nb) bs[t] = lds[t] - v;
}

__global__ __launch_bounds__(256) void scan3_kernel(
    int* __restrict__ rowStart, int* __restrict__ cursor,
    const int* __restrict__ blockSums, int n, int e)
{
    const int i = blockIdx.x * blockDim.x + threadIdx.x;
    if (i < n) {
        const int v = rowStart[i] + blockSums[i >> 10];
        rowStart[i] = v;
        cursor[i] = v;
    }
    if (i == 0) rowStart[n] = e;
}

// XCD-partitioned scatter with non-temporal streaming reads.
// Stored value is pre-scaled by 0.5 (folds the beta blend into scatter).
__global__ __launch_bounds__(256) void scatter_part_kernel(
    const int* __restrict__ erow, const int* __restrict__ ecol,
    const float* __restrict__ eval_, int* __restrict__ cursor,
    int2* __restrict__ cv, int e, int rlo_chunk)
{
    const int part = blockIdx.x & 7;
    const int bip  = blockIdx.x >> 3;
    const int nbp  = gridDim.x >> 3;
    const int rlo = part * rlo_chunk;
    const int rhi = rlo + rlo_chunk;

    int idx = bip * blockDim.x + threadIdx.x;
    const int stride = nbp * blockDim.x;
    for (int i = idx; i < e; i += stride) {
        const int r = nt_i(&erow[i]);
        if (r >= rlo && r < rhi) {
            const int c = nt_i(&ecol[i]);
            const float v = 0.5f * nt_f(&eval_[i]);
            const int p = atomicAdd(&cursor[r], 1);
            cv[p] = make_int2(c, __float_as_int(v));
        }
    }
}

// ---------------- Aggregate v2 ---------------------------------------------
// One wave per row. 16 lanes per edge (4 edges per wave-load), each lane
// loads ushort4 (8B) of the gathered support row. cv reads hit L2 (no nt!).
__global__ __launch_bounds__(256) void aggregate_kernel(
    const int* __restrict__ rowStart, const int2* __restrict__ cv,
    const __hip_bfloat16* __restrict__ sup_bf, float* __restrict__ out, int n)
{
    const int row = blockIdx.x * 4 + (threadIdx.x >> 6);
    if (row >= n) return;
    const int lane = threadIdx.x & 63;
    const int g   = lane >> 4;    // edge subgroup 0..3
    const int sub = lane & 15;    // col group: cols 4*sub .. 4*sub+3

    const int s = rowStart[row], e = rowStart[row + 1];
    float4 acc = make_float4(0.f, 0.f, 0.f, 0.f);

    int i = s;
    #define AGG_BUNDLE_FULL(ii)                                               \
    {                                                                         \
        const int2 q = cv[(ii) + g];                                          \
        const float v = __int_as_float(q.y);                                  \
        const ushort4 u = *(const ushort4*)&sup_bf[(size_t)q.x * DIM + sub * 4]; \
        acc.x = fmaf(v, bfbits(u.x), acc.x);                                  \
        acc.y = fmaf(v, bfbits(u.y), acc.y);                                  \
        acc.z = fmaf(v, bfbits(u.z), acc.z);                                  \
        acc.w = fmaf(v, bfbits(u.w), acc.w);                                  \
    }
    for (; i + 8 <= e; i += 8) {
        AGG_BUNDLE_FULL(i);
        AGG_BUNDLE_FULL(i + 4);
    }
    if (i + 4 <= e) {
        AGG_BUNDLE_FULL(i);
        i += 4;
    }
    if (i < e) {
        const int idx = i + g;
        const int2 q = cv[min(idx, e - 1)];
        const float v = (idx < e) ? __int_as_float(q.y) : 0.f;
        const ushort4 u = *(const ushort4*)&sup_bf[(size_t)q.x * DIM + sub * 4];
        acc.x = fmaf(v, bfbits(u.x), acc.x);
        acc.y = fmaf(v, bfbits(u.y), acc.y);
        acc.z = fmaf(v, bfbits(u.z), acc.z);
        acc.w = fmaf(v, bfbits(u.w), acc.w);
    }
    #undef AGG_BUNDLE_FULL

    acc.x += __shfl_xor(acc.x, 16, 64);
    acc.y += __shfl_xor(acc.y, 16, 64);
    acc.z += __shfl_xor(acc.z, 16, 64);
    acc.w += __shfl_xor(acc.w, 16, 64);
    acc.x += __shfl_xor(acc.x, 32, 64);
    acc.y += __shfl_xor(acc.y, 32, 64);
    acc.z += __shfl_xor(acc.z, 32, 64);
    acc.w += __shfl_xor(acc.w, 32, 64);

    if (g == 0) {
        float4* po = (float4*)&out[(size_t)row * DIM + sub * 4];
        float4 o = *po;   // dense-branch result (already halved)
        o.x += acc.x; o.y += acc.y; o.z += acc.z; o.w += acc.w;
        *po = o;
    }
}

// ---------------- Fallback (atomic path, f32 support) ----------------------
__global__ __launch_bounds__(256) void support_f32_kernel(
    const float* __restrict__ x, const float* __restrict__ h0,
    float* __restrict__ sup, long total4)
{
    long idx = (long)blockIdx.x * blockDim.x + threadIdx.x;
    const long stride = (long)gridDim.x * blockDim.x;
    for (long t = idx; t < total4; t += stride) {
        const float4 xv = ((const float4*)x)[t];
        const float4 hv = ((const float4*)h0)[t];
        float4 s;
        s.x = 0.9f * xv.x + 0.1f * hv.x;
        s.y = 0.9f * xv.y + 0.1f * hv.y;
        s.z = 0.9f * xv.z + 0.1f * hv.z;
        s.w = 0.9f * xv.w + 0.1f * hv.w;
        ((float4*)sup)[t] = s;
    }
}

__global__ __launch_bounds__(256) void dense_gemm_f32_kernel(
    const float* __restrict__ sup, const float* __restrict__ weight,
    float* __restrict__ out, int n)
{
    __shared__ float s_tile[64][68];
    __shared__ float w_tile[64][68];
    const int tid = threadIdx.x;
    for (int i = tid; i < 64 * 64; i += 256)
        w_tile[i >> 6][i & 63] = weight[i];
    const int row0 = blockIdx.x * 64;
    for (int p = tid; p < 2048; p += 256) {
        const int r = p >> 5;
        const int c = (p & 31) << 1;
        const int row = row0 + r;
        float2 s2 = make_float2(0.f, 0.f);
        if (row < n) s2 = *(const float2*)&sup[(size_t)row * DIM + c];
        s_tile[r][c] = s2.x; s_tile[r][c + 1] = s2.y;
    }
    __syncthreads();
    const int tx = tid & 15, ty = tid >> 4;
    const int r0 = ty * 4, c0 = tx * 4;
    float acc[4][4] = {};
    #pragma unroll 2
    for (int k = 0; k < 64; k += 4) {
        float4 a[4], b[4];
        #pragma unroll
        for (int i = 0; i < 4; ++i) a[i] = *(const float4*)&s_tile[r0 + i][k];
        #pragma unroll
        for (int j = 0; j < 4; ++j) b[j] = *(const float4*)&w_tile[k + j][c0];
        #pragma unroll
        for (int i = 0; i < 4; ++i) {
            acc[i][0] = fmaf(a[i].x, b[0].x, acc[i][0]);
            acc[i][1] = fmaf(a[i].x, b[0].y, acc[i][1]);
            acc[i][2] = fmaf(a[i].x, b[0].z, acc[i][2]);
            acc[i][3] = fmaf(a[i].x, b[0].w, acc[i][3]);
            acc[i][0] = fmaf(a[i].y, b[1].x, acc[i][0]);
            acc[i][1] = fmaf(a[i].y, b[1].y, acc[i][1]);
            acc[i][2] = fmaf(a[i].y, b[1].z, acc[i][2]);
            acc[i][3] = fmaf(a[i].y, b[1].w, acc[i][3]);
            acc[i][0] = fmaf(a[i].z, b[2].x, acc[i][0]);
            acc[i][1] = fmaf(a[i].z, b[2].y, acc[i][1]);
            acc[i][2] = fmaf(a[i].z, b[2].z, acc[i][2]);
            acc[i][3] = fmaf(a[i].z, b[2].w, acc[i][3]);
            acc[i][0] = fmaf(a[i].w, b[3].x, acc[i][0]);
            acc[i][1] = fmaf(a[i].w, b[3].y, acc[i][1]);
            acc[i][2] = fmaf(a[i].w, b[3].z, acc[i][2]);
            acc[i][3] = fmaf(a[i].w, b[3].w, acc[i][3]);
        }
    }
    #pragma unroll
    for (int i = 0; i < 4; ++i) {
        const int row = row0 + r0 + i;
        if (row < n) {
            float4 o;
            o.x = 0.5f * acc[i][0]; o.y = 0.5f * acc[i][1];
            o.z = 0.5f * acc[i][2]; o.w = 0.5f * acc[i][3];
            *(float4*)&out[(size_t)row * DIM + c0] = o;
        }
    }
}

__global__ __launch_bounds__(256) void spmm_atomic_kernel(
    const int* __restrict__ erow, const int* __restrict__ ecol,
    const float* __restrict__ eval_, const float* __restrict__ support,
    float* __restrict__ out, int e)
{
    const long total = (long)e * DIM;
    long idx = (long)blockIdx.x * blockDim.x + threadIdx.x;
    const long stride = (long)gridDim.x * blockDim.x;
    for (long t = idx; t < total; t += stride) {
        const int edge = (int)(t >> 6);
        const int j = (int)(t & 63);
        const float m = 0.5f * eval_[edge] * support[(long)ecol[edge] * DIM + j];
        atomicAdd(&out[(long)erow[edge] * DIM + j], m);
    }
}

extern "C" void kernel_launch(void* const* d_in, const int* in_sizes, int n_in,
                              void* d_out, int out_size, void* d_ws, size_t ws_size,
                              hipStream_t stream) {
    const float* x      = (const float*)d_in[0];
    const float* h0     = (const float*)d_in[1];
    const int*   erow   = (const int*)d_in[2];
    const int*   ecol   = (const int*)d_in[3];
    const float* eval_  = (const float*)d_in[4];
    const float* weight = (const float*)d_in[5];
    float* out = (float*)d_out;

    const int n = in_sizes[0] / DIM;
    const int e = in_sizes[2];

    char* wsb = (char*)d_ws;
    size_t off = 0;
    auto alloc = [&](size_t bytes) { size_t o = off; off = (off + bytes + 255) & ~255ULL; return o; };
    const size_t o_supbf = alloc((size_t)n * DIM * 2);
    const size_t o_cv    = alloc((size_t)e * 8);
    const size_t o_rowst = alloc((size_t)(n + 1) * 4);
    const size_t o_curs  = alloc((size_t)n * 4);
    const size_t o_cnts  = alloc((size_t)n * 4);
    const size_t o_bsums = alloc(512);
    const size_t need = off;

    const int nb1 = (n + 1023) / 1024;
    const long total4 = (long)n * DIM / 4;

    if (ws_size >= need && nb1 <= 128) {
        __hip_bfloat16* sup_bf = (__hip_bfloat16*)(wsb + o_supbf);
        int2* cv      = (int2*)(wsb + o_cv);
        int* rowStart = (int*)(wsb + o_rowst);
        int* cursor   = (int*)(wsb + o_curs);
        int* counts   = (int*)(wsb + o_cnts);
        int* bsums    = (int*)(wsb + o_bsums);

        (void)hipMemsetAsync(counts, 0, (size_t)n * 4, stream);

        support_bf16_kernel<<<2048, 256, 0, stream>>>(x, h0, sup_bf, total4);
        hist_kernel<<<2048, 256, 0, stream>>>(erow, counts, e);
        scan1_kernel<<<nb1, 256, 0, stream>>>(counts, rowStart, bsums, n);
        scan2_kernel<<<1, 128, 0, stream>>>(bsums, nb1);
        scan3_kernel<<<(n + 255) / 256, 256, 0, stream>>>(rowStart, cursor, bsums, n, e);

        dense_gemm_kernel<<<(n + 63) / 64, 256, 0, stream>>>(sup_bf, weight, out, n);

        const int rchunk = (n + 7) / 8;
        scatter_part_kernel<<<4096, 256, 0, stream>>>(erow, ecol, eval_, cursor, cv, e, rchunk);

        aggregate_kernel<<<(n + 3) / 4, 256, 0, stream>>>(rowStart, cv, sup_bf, out, n);
    } else {
        float* support = (float*)d_ws;
        support_f32_kernel<<<2048, 256, 0, stream>>>(x, h0, support, total4);
        dense_gemm_f32_kernel<<<(n + 63) / 64, 256, 0, stream>>>(support, weight, out, n);
        spmm_atomic_kernel<<<16384, 256, 0, stream>>>(erow, ecol, eval_, support, out, e);
    }
}